// Round 14
// baseline (1934.166 us; speedup 1.0000x reference)
//
#include <hip/hip_runtime.h>
#include <math.h>

#define B_  4
#define S_  1024
#define D_  2048
#define NL_ 2
#define H_  16
#define KV_ 4
#define F_  8192
#define R_  16
#define HD_ 128
#define BS_ (B_*S_)   // 4096 tokens
#define QT2 32
#define KBLK 64
#define NQKV 3072     // q(2048) + k(512) + v(512)

typedef unsigned short u16;
typedef __attribute__((ext_vector_type(8))) __bf16 bf16x8;
typedef __attribute__((ext_vector_type(4))) float  f32x4;

__device__ __forceinline__ u16 f2bf(float f) {
    unsigned x = __float_as_uint(f);
    unsigned r = (x + 0x7fffu + ((x >> 16) & 1u)) >> 16;   // RNE
    return (u16)r;
}
__device__ __forceinline__ float bf2f(u16 u) {
    return __uint_as_float(((unsigned)u) << 16);
}

// async global->LDS, 16B per lane. LDS dest must be linear (base + lane*16).
__device__ __forceinline__ void gload16(const void* g, void* l) {
    __builtin_amdgcn_global_load_lds((const __attribute__((address_space(1))) void*)g,
                                     (__attribute__((address_space(3))) void*)l, 16, 0, 0);
}

// ------------------------------------------------------------------
__global__ void embed_kernel(const float* __restrict__ embed,
                             const int* __restrict__ ids,
                             float* __restrict__ x) {
    int tok = blockIdx.x;
    int id  = ids[tok];
    const float4* src = (const float4*)(embed + (size_t)id * D_);
    float4*       dst = (float4*)(x + (size_t)tok * D_);
    for (int i = threadIdx.x; i < D_/4; i += blockDim.x) dst[i] = src[i];
}

// ------------------------------------------------------------------
template<int OUTBF>
__global__ __launch_bounds__(256) void rmsnorm_kernel(const float* __restrict__ x,
                                                      const float* __restrict__ w,
                                                      void* __restrict__ out) {
    int row = blockIdx.x;
    const float4* xr = (const float4*)(x + (size_t)row * D_);
    float ss = 0.f;
    for (int i = threadIdx.x; i < D_/4; i += 256) {
        float4 v = xr[i];
        ss += v.x*v.x + v.y*v.y + v.z*v.z + v.w*v.w;
    }
    __shared__ float red[4];
    for (int off = 32; off; off >>= 1) ss += __shfl_down(ss, off);
    if ((threadIdx.x & 63) == 0) red[threadIdx.x >> 6] = ss;
    __syncthreads();
    float tot = red[0] + red[1] + red[2] + red[3];
    float scale = rsqrtf(tot / (float)D_ + 1e-5f);
    const float4* w4 = (const float4*)w;
    for (int i = threadIdx.x; i < D_/4; i += 256) {
        float4 v = xr[i], g = w4[i];
        float a = v.x*scale*g.x, b = v.y*scale*g.y, c = v.z*scale*g.z, d = v.w*scale*g.w;
        if (OUTBF) {
            ushort4 o; o.x = f2bf(a); o.y = f2bf(b); o.z = f2bf(c); o.w = f2bf(d);
            ((ushort4*)((u16*)out + (size_t)row * D_))[i] = o;
        } else {
            float4 o; o.x = a; o.y = b; o.z = c; o.w = d;
            ((float4*)((float*)out + (size_t)row * D_))[i] = o;
        }
    }
}

// ------------------------------------------------------------------
// 64x64 transpose + f32->bf16: in [K][N] f32 -> out [N][K] bf16
__global__ __launch_bounds__(256) void convt_kernel(const float* __restrict__ in,
                                                    u16* __restrict__ outT,
                                                    int K, int N) {
    __shared__ float tile[64][65];
    int k0 = blockIdx.y * 64, n0 = blockIdx.x * 64;
    int t = threadIdx.x, r = t >> 4, c4 = (t & 15) * 4;
    #pragma unroll
    for (int p = 0; p < 4; p++) {
        float4 v = *(const float4*)(in + (size_t)(k0 + p * 16 + r) * N + n0 + c4);
        tile[p*16+r][c4]   = v.x; tile[p*16+r][c4+1] = v.y;
        tile[p*16+r][c4+2] = v.z; tile[p*16+r][c4+3] = v.w;
    }
    __syncthreads();
    #pragma unroll
    for (int p = 0; p < 4; p++) {
        int n = p * 16 + r;
        ushort4 o;
        o.x = f2bf(tile[c4][n]);   o.y = f2bf(tile[c4+1][n]);
        o.z = f2bf(tile[c4+2][n]); o.w = f2bf(tile[c4+3][n]);
        *(ushort4*)(outT + (size_t)(n0 + n) * K + k0 + c4) = o;
    }
}

// fused wq/wk/wv/wo transpose-convert into WqkvoT (o at rows 3072..5120).
__global__ __launch_bounds__(256) void convt_qkv(const float* __restrict__ wq,
                                                 const float* __restrict__ wk,
                                                 const float* __restrict__ wv,
                                                 const float* __restrict__ wo,
                                                 u16* __restrict__ outT) {
    int z = blockIdx.z;
    int N = (z == 0 || z == 3) ? 2048 : 512;
    if (blockIdx.x * 64 >= N) return;
    const float* in = (z == 0) ? wq : (z == 1 ? wk : (z == 2 ? wv : wo));
    size_t roff = (z == 0) ? 0 : (z == 1 ? 2048 : (z == 2 ? 2560 : 3072));
    u16* out = outT + roff * D_;
    __shared__ float tile[64][65];
    int k0 = blockIdx.y * 64, n0 = blockIdx.x * 64;
    int t = threadIdx.x, r = t >> 4, c4 = (t & 15) * 4;
    #pragma unroll
    for (int p = 0; p < 4; p++) {
        float4 v = *(const float4*)(in + (size_t)(k0 + p * 16 + r) * N + n0 + c4);
        tile[p*16+r][c4]   = v.x; tile[p*16+r][c4+1] = v.y;
        tile[p*16+r][c4+2] = v.z; tile[p*16+r][c4+3] = v.w;
    }
    __syncthreads();
    #pragma unroll
    for (int p = 0; p < 4; p++) {
        int n = p * 16 + r;
        ushort4 o;
        o.x = f2bf(tile[c4][n]);   o.y = f2bf(tile[c4+1][n]);
        o.z = f2bf(tile[c4+2][n]); o.w = f2bf(tile[c4+3][n]);
        *(ushort4*)(out + (size_t)(n0 + n) * D_ + k0 + c4) = o;
    }
}

// ------------------------------------------------------------------
// MFMA GEMM, B transposed, bf16 output: C[M,N] = A @ Bt^T (qkv projection)
__global__ __launch_bounds__(256) void gemm_bt_bf16(const u16* __restrict__ A,
                                                    const u16* __restrict__ Bt,
                                                    u16* __restrict__ C,
                                                    int N, int K) {
    __shared__ __align__(16) u16 As[128*64];
    __shared__ __align__(16) u16 Bs[128*64];
    int tid = threadIdx.x, lane = tid & 63;
    int wid = tid >> 6, wm = wid >> 1, wn = wid & 1;
    int m0 = blockIdx.y * 128, n0 = blockIdx.x * 128;
    const u16* Ab = A  + (size_t)m0 * K;
    const u16* Bb = Bt + (size_t)n0 * K;
    f32x4 acc[4][4] = {};
    for (int k0 = 0; k0 < K; k0 += 64) {
        #pragma unroll
        for (int qq = 0; qq < 4; qq++) {
            int u = qq * 256 + tid;
            int row = u >> 3, cu = u & 7, scu = cu ^ (row & 7);
            size_t goff = (size_t)row * K + k0 + scu * 8;
            gload16(Ab + goff, (char*)As + u * 16);
            gload16(Bb + goff, (char*)Bs + u * 16);
        }
        __syncthreads();
        #pragma unroll
        for (int kk = 0; kk < 2; kk++) {
            int cu = kk * 4 + (lane >> 4);
            bf16x8 af[4], bfr[4];
            #pragma unroll
            for (int i = 0; i < 4; i++) {
                int ar = wm * 64 + i * 16 + (lane & 15);
                af[i]  = *(const bf16x8*)((const char*)As + (((ar << 3) | (cu ^ (ar & 7))) << 4));
                int br = wn * 64 + i * 16 + (lane & 15);
                bfr[i] = *(const bf16x8*)((const char*)Bs + (((br << 3) | (cu ^ (br & 7))) << 4));
            }
            #pragma unroll
            for (int i = 0; i < 4; i++)
                #pragma unroll
                for (int j = 0; j < 4; j++)
                    acc[i][j] = __builtin_amdgcn_mfma_f32_16x16x32_bf16(af[i], bfr[j], acc[i][j], 0, 0, 0);
        }
        __syncthreads();
    }
    int r0 = (lane >> 4) * 4, c0 = lane & 15;
    #pragma unroll
    for (int i = 0; i < 4; i++)
        #pragma unroll
        for (int j = 0; j < 4; j++) {
            int row = m0 + wm * 64 + i * 16 + r0;
            int col = n0 + wn * 64 + j * 16 + c0;
            u16* cp = C + (size_t)row * N + col;
            #pragma unroll
            for (int r = 0; r < 4; r++)
                cp[(size_t)r * N] = f2bf(acc[i][j][r]);
        }
}

// ------------------------------------------------------------------
// 256x256 fused gate/up GEMM over W' [16384][2048], 4-phase ring schedule.
__global__ __launch_bounds__(512) void gemm_gateup8(const u16* __restrict__ A,
                                                    const u16* __restrict__ Wt,
                                                    u16* __restrict__ act,
                                                    int Nact, int K) {
    __shared__ __align__(16) u16 ring[2][4][8192];   // [op][slot] 16KB slots = 128 KiB
    int tid = threadIdx.x, lane = tid & 63;
    int w = tid >> 6;
    int wm = w >> 2, wn = w & 3;
    int g = lane >> 4, li = lane & 15;
    int m0 = blockIdx.y * 256, n0 = blockIdx.x * 256;
    const u16* Ab = A  + (size_t)m0 * K;
    const u16* Bb = Wt + (size_t)n0 * K;
    int nt = K >> 6;

    f32x4 acc[8][4] = {};

    #define STG(s, t_, kh, P)                                                        \
        do {                                                                         \
            int u_ = (P) * 512 + tid;                                                \
            int j_ = u_ >> 3, cc_ = u_ & 7;                                          \
            int sc_ = cc_ ^ (j_ & 7);                                                \
            int row_ = 2 * j_ + (sc_ >> 2);                                          \
            int kc_ = (t_) * 64 + (kh) * 32 + (sc_ & 3) * 8;                         \
            gload16(Ab + (size_t)row_ * K + kc_, (char*)&ring[0][s][0] + u_ * 16);   \
            gload16(Bb + (size_t)row_ * K + kc_, (char*)&ring[1][s][0] + u_ * 16);   \
        } while (0)

    #define FRAG(op, s, r) (*(const bf16x8*)((const char*)&ring[op][s][0] +          \
        (((((r) >> 1) << 3) | (((((r) & 1) << 2) | g) ^ (((r) >> 1) & 7))) << 4)))

    STG(0, 0, 0, 0); STG(0, 0, 0, 1);
    STG(1, 0, 1, 0); STG(1, 0, 1, 1);
    STG(2, 1, 0, 0); STG(2, 1, 0, 1);

    for (int t = 0; t < nt; t++) {
        int s0  = (2 * t) & 3;
        int s1  = (2 * t + 1) & 3;
        int sW0 = (2 * t + 3) & 3;
        int sW1 = s0;
        bf16x8 afA[4], afB[4], bfr[4];

        // ---- phase 0 ----
        if (t == nt - 1) asm volatile("s_waitcnt vmcnt(4)" ::: "memory");
        else             asm volatile("s_waitcnt vmcnt(8)" ::: "memory");
        __builtin_amdgcn_s_barrier();
        __builtin_amdgcn_sched_barrier(0);
        #pragma unroll
        for (int j = 0; j < 4; j++) bfr[j] = FRAG(1, s0, wn * 64 + j * 16 + li);
        #pragma unroll
        for (int i = 0; i < 4; i++) afA[i] = FRAG(0, s0, wm * 128 + i * 16 + li);
        if (t + 1 < nt) STG(sW0, t + 1, 1, 0);
        asm volatile("s_waitcnt lgkmcnt(0)" ::: "memory");
        __builtin_amdgcn_sched_barrier(0);
        __builtin_amdgcn_s_setprio(1);
        #pragma unroll
        for (int i = 0; i < 4; i++)
            #pragma unroll
            for (int j = 0; j < 4; j++)
                acc[i][j] = __builtin_amdgcn_mfma_f32_16x16x32_bf16(afA[i], bfr[j], acc[i][j], 0, 0, 0);
        __builtin_amdgcn_s_setprio(0);
        #pragma unroll
        for (int i = 0; i < 4; i++) afB[i] = FRAG(0, s0, wm * 128 + 64 + i * 16 + li);
        __builtin_amdgcn_sched_barrier(0);

        // ---- phase 1 ----
        __builtin_amdgcn_s_barrier();
        __builtin_amdgcn_sched_barrier(0);
        if (t + 1 < nt) STG(sW0, t + 1, 1, 1);
        asm volatile("s_waitcnt lgkmcnt(0)" ::: "memory");
        __builtin_amdgcn_sched_barrier(0);
        __builtin_amdgcn_s_setprio(1);
        #pragma unroll
        for (int i = 0; i < 4; i++)
            #pragma unroll
            for (int j = 0; j < 4; j++)
                acc[4 + i][j] = __builtin_amdgcn_mfma_f32_16x16x32_bf16(afB[i], bfr[j], acc[4 + i][j], 0, 0, 0);
        __builtin_amdgcn_s_setprio(0);

        // ---- phase 2 ----
        if (t == nt - 1) asm volatile("s_waitcnt vmcnt(0)" ::: "memory");
        else             asm volatile("s_waitcnt vmcnt(8)" ::: "memory");
        __builtin_amdgcn_s_barrier();
        __builtin_amdgcn_sched_barrier(0);
        #pragma unroll
        for (int j = 0; j < 4; j++) bfr[j] = FRAG(1, s1, wn * 64 + j * 16 + li);
        #pragma unroll
        for (int i = 0; i < 4; i++) afA[i] = FRAG(0, s1, wm * 128 + i * 16 + li);
        if (t + 2 < nt) STG(sW1, t + 2, 0, 0);
        asm volatile("s_waitcnt lgkmcnt(0)" ::: "memory");
        __builtin_amdgcn_sched_barrier(0);
        __builtin_amdgcn_s_setprio(1);
        #pragma unroll
        for (int i = 0; i < 4; i++)
            #pragma unroll
            for (int j = 0; j < 4; j++)
                acc[i][j] = __builtin_amdgcn_mfma_f32_16x16x32_bf16(afA[i], bfr[j], acc[i][j], 0, 0, 0);
        __builtin_amdgcn_s_setprio(0);
        #pragma unroll
        for (int i = 0; i < 4; i++) afB[i] = FRAG(0, s1, wm * 128 + 64 + i * 16 + li);
        __builtin_amdgcn_sched_barrier(0);

        // ---- phase 3 ----
        __builtin_amdgcn_s_barrier();
        __builtin_amdgcn_sched_barrier(0);
        if (t + 2 < nt) STG(sW1, t + 2, 0, 1);
        asm volatile("s_waitcnt lgkmcnt(0)" ::: "memory");
        __builtin_amdgcn_sched_barrier(0);
        __builtin_amdgcn_s_setprio(1);
        #pragma unroll
        for (int i = 0; i < 4; i++)
            #pragma unroll
            for (int j = 0; j < 4; j++)
                acc[4 + i][j] = __builtin_amdgcn_mfma_f32_16x16x32_bf16(afB[i], bfr[j], acc[4 + i][j], 0, 0, 0);
        __builtin_amdgcn_s_setprio(0);
    }
    #undef STG
    #undef FRAG

    // ---- epilogue: U-waves dump acc to LDS, G-waves fuse silu(g)*u ----
    __syncthreads();
    float* X = (float*)&ring[0][0][0];
    if (wn >= 2) {
        float* Rr = X + (size_t)(wm * 2 + (wn - 2)) * 8192;
        #pragma unroll
        for (int i = 0; i < 8; i++)
            #pragma unroll
            for (int j = 0; j < 4; j++)
                #pragma unroll
                for (int r = 0; r < 4; r++) {
                    int row = i * 16 + g * 4 + r;
                    int col = j * 16 + li;
                    Rr[row * 64 + (col ^ (((row >> 2) & 3) << 4))] = acc[i][j][r];
                }
    }
    __syncthreads();
    if (wn < 2) {
        const float* Rr = X + (size_t)(wm * 2 + wn) * 8192;
        int colbase = (n0 >> 1) + wn * 64;
        #pragma unroll
        for (int i = 0; i < 8; i++)
            #pragma unroll
            for (int j = 0; j < 4; j++)
                #pragma unroll
                for (int r = 0; r < 4; r++) {
                    int row = i * 16 + g * 4 + r;
                    int col = j * 16 + li;
                    float gv = acc[i][j][r];
                    float uv = Rr[row * 64 + (col ^ (((row >> 2) & 3) << 4))];
                    float s = gv / (1.f + __expf(-gv));
                    act[(size_t)(m0 + wm * 128 + row) * Nact + colbase + col] = f2bf(s * uv);
                }
    }
}

// ------------------------------------------------------------------
// ring GEMM (ACC += into f32 C): M256 x N128 tile, 4-slot ring, 2 phases/K-tile,
// counted vmcnt(6). Used for down projection AND o projection.
__global__ __launch_bounds__(512) void gemm_down_ring(const u16* __restrict__ A,
                                                      const u16* __restrict__ Bt,
                                                      float* __restrict__ C,
                                                      int N, int K) {
    __shared__ __align__(16) u16 ringA[4][8192];
    __shared__ __align__(16) u16 ringB[4][4096];
    int tid = threadIdx.x, lane = tid & 63;
    int w = tid >> 6;
    int wm = w >> 1, wn = w & 1;
    int g = lane >> 4, li = lane & 15;
    int m0 = blockIdx.y * 256, n0 = blockIdx.x * 128;
    const u16* Ab = A  + (size_t)m0 * K;
    const u16* Bb = Bt + (size_t)n0 * K;
    int nt = K >> 6;

    f32x4 acc[4][4] = {};

    #define STGA(s, t_, kh, P)                                                       \
        do {                                                                         \
            int u_ = (P) * 512 + tid;                                                \
            int j_ = u_ >> 3, cc_ = u_ & 7;                                          \
            int sc_ = cc_ ^ (j_ & 7);                                                \
            int row_ = 2 * j_ + (sc_ >> 2);                                          \
            int kc_ = (t_) * 64 + (kh) * 32 + (sc_ & 3) * 8;                         \
            gload16(Ab + (size_t)row_ * K + kc_, (char*)&ringA[s][0] + u_ * 16);     \
        } while (0)
    #define STGB(s, t_, kh)                                                          \
        do {                                                                         \
            int u_ = tid;                                                            \
            int j_ = u_ >> 3, cc_ = u_ & 7;                                          \
            int sc_ = cc_ ^ (j_ & 7);                                                \
            int row_ = 2 * j_ + (sc_ >> 2);                                          \
            int kc_ = (t_) * 64 + (kh) * 32 + (sc_ & 3) * 8;                         \
            gload16(Bb + (size_t)row_ * K + kc_, (char*)&ringB[s][0] + u_ * 16);     \
        } while (0)

    #define FRAGA(s, r) (*(const bf16x8*)((const char*)&ringA[s][0] +                \
        (((((r) >> 1) << 3) | (((((r) & 1) << 2) | g) ^ (((r) >> 1) & 7))) << 4)))
    #define FRAGB(s, r) (*(const bf16x8*)((const char*)&ringB[s][0] +                \
        (((((r) >> 1) << 3) | (((((r) & 1) << 2) | g) ^ (((r) >> 1) & 7))) << 4)))

    STGA(0, 0, 0, 0); STGA(0, 0, 0, 1); STGB(0, 0, 0);
    STGA(1, 0, 1, 0); STGA(1, 0, 1, 1); STGB(1, 0, 1);
    STGA(2, 1, 0, 0); STGA(2, 1, 0, 1); STGB(2, 1, 0);

    for (int t = 0; t < nt; t++) {
        int s0  = (2 * t) & 3;
        int s1  = (2 * t + 1) & 3;
        int sW0 = (2 * t + 3) & 3;
        int sW1 = s0;
        bf16x8 af[4], bfr[4];

        // ---- phase 0: kh0 ----
        if (t == nt - 1) asm volatile("s_waitcnt vmcnt(3)" ::: "memory");
        else             asm volatile("s_waitcnt vmcnt(6)" ::: "memory");
        __builtin_amdgcn_s_barrier();
        __builtin_amdgcn_sched_barrier(0);
        #pragma unroll
        for (int j = 0; j < 4; j++) bfr[j] = FRAGB(s0, wn * 64 + j * 16 + li);
        #pragma unroll
        for (int i = 0; i < 4; i++) af[i] = FRAGA(s0, wm * 64 + i * 16 + li);
        if (t + 1 < nt) { STGA(sW0, t + 1, 1, 0); STGA(sW0, t + 1, 1, 1); STGB(sW0, t + 1, 1); }
        asm volatile("s_waitcnt lgkmcnt(0)" ::: "memory");
        __builtin_amdgcn_sched_barrier(0);
        __builtin_amdgcn_s_setprio(1);
        #pragma unroll
        for (int i = 0; i < 4; i++)
            #pragma unroll
            for (int j = 0; j < 4; j++)
                acc[i][j] = __builtin_amdgcn_mfma_f32_16x16x32_bf16(af[i], bfr[j], acc[i][j], 0, 0, 0);
        __builtin_amdgcn_s_setprio(0);

        // ---- phase 1: kh1 ----
        if (t == nt - 1) asm volatile("s_waitcnt vmcnt(0)" ::: "memory");
        else             asm volatile("s_waitcnt vmcnt(6)" ::: "memory");
        __builtin_amdgcn_s_barrier();
        __builtin_amdgcn_sched_barrier(0);
        #pragma unroll
        for (int j = 0; j < 4; j++) bfr[j] = FRAGB(s1, wn * 64 + j * 16 + li);
        #pragma unroll
        for (int i = 0; i < 4; i++) af[i] = FRAGA(s1, wm * 64 + i * 16 + li);
        if (t + 2 < nt) { STGA(sW1, t + 2, 0, 0); STGA(sW1, t + 2, 0, 1); STGB(sW1, t + 2, 0); }
        asm volatile("s_waitcnt lgkmcnt(0)" ::: "memory");
        __builtin_amdgcn_sched_barrier(0);
        __builtin_amdgcn_s_setprio(1);
        #pragma unroll
        for (int i = 0; i < 4; i++)
            #pragma unroll
            for (int j = 0; j < 4; j++)
                acc[i][j] = __builtin_amdgcn_mfma_f32_16x16x32_bf16(af[i], bfr[j], acc[i][j], 0, 0, 0);
        __builtin_amdgcn_s_setprio(0);
    }
    #undef STGA
    #undef STGB
    #undef FRAGA
    #undef FRAGB

    int r0 = g * 4, c0 = li;
    #pragma unroll
    for (int i = 0; i < 4; i++)
        #pragma unroll
        for (int j = 0; j < 4; j++) {
            int row = m0 + wm * 64 + i * 16 + r0;
            int col = n0 + wn * 64 + j * 16 + c0;
            float* cp = C + (size_t)row * N + col;
            #pragma unroll
            for (int r = 0; r < 4; r++)
                cp[(size_t)r * N] += acc[i][j][r];
        }
}

// ------------------------------------------------------------------
// LoRA-A, fused q+v (h is bf16)
__global__ __launch_bounds__(256) void lora_a2(const u16* __restrict__ h,
                                               const float* __restrict__ laq,
                                               const float* __restrict__ lav,
                                               float* __restrict__ t16q,
                                               float* __restrict__ t16v) {
    const float* la = blockIdx.y ? lav : laq;
    float* t16 = blockIdx.y ? t16v : t16q;
    int r = threadIdx.x >> 4;
    int c = threadIdx.x & 15;
    int row = blockIdx.x * 16 + r;
    const ushort4* hr = (const ushort4*)(h + (size_t)row * D_);
    const float4* lr = (const float4*)(la + (size_t)c * D_);
    float acc = 0.f;
    #pragma unroll 4
    for (int i = 0; i < D_/4; i++) {
        ushort4 a = hr[i]; float4 b = lr[i];
        acc += bf2f(a.x)*b.x + bf2f(a.y)*b.y + bf2f(a.z)*b.z + bf2f(a.w)*b.w;
    }
    t16[(size_t)row * R_ + c] = acc;
}

// ------------------------------------------------------------------
// fused q-LoRA-B + RoPE from bf16 qkv buffer. grid (BS, 5), 256 thr = 4 heads.
__global__ __launch_bounds__(256) void qkconv_rope(const u16* __restrict__ qkvb,
                                                   const float* __restrict__ t16q,
                                                   const float* __restrict__ lbq,
                                                   u16* __restrict__ Qc, u16* __restrict__ Kc) {
    int tok = blockIdx.x;
    int hh  = blockIdx.y * 4 + (threadIdx.x >> 6);
    int t   = threadIdx.x & 63;
    int b = tok >> 10, s = tok & (S_ - 1);
    __shared__ float ts[R_];
    if (threadIdx.x < R_) ts[threadIdx.x] = t16q[(size_t)tok * R_ + threadIdx.x];
    __syncthreads();
    float inv = __expf(-(float)t * (13.122363377404328f / 64.0f));
    float f = (float)s * inv;
    float c = __cosf(f), si = __sinf(f);
    float x0, x1;
    u16* dst;
    if (hh < H_) {
        const u16* src = qkvb + (size_t)tok * NQKV + hh * HD_;
        int d0 = hh * HD_ + t;
        float l0 = 0.f, l1 = 0.f;
        const float4* b0 = (const float4*)(lbq + (size_t)d0 * R_);
        const float4* b1 = (const float4*)(lbq + (size_t)(d0 + 64) * R_);
        #pragma unroll
        for (int r4 = 0; r4 < 4; r4++) {
            float4 v0 = b0[r4], v1 = b1[r4];
            l0 += v0.x*ts[r4*4] + v0.y*ts[r4*4+1] + v0.z*ts[r4*4+2] + v0.w*ts[r4*4+3];
            l1 += v1.x*ts[r4*4] + v1.y*ts[r4*4+1] + v1.z*ts[r4*4+2] + v1.w*ts[r4*4+3];
        }
        x0 = bf2f(src[t]) + 2.0f * l0;
        x1 = bf2f(src[t + 64]) + 2.0f * l1;
        dst = Qc + (((size_t)(b * H_ + hh)) * S_ + s) * HD_;
    } else {
        int kh = hh - H_;
        const u16* src = qkvb + (size_t)tok * NQKV + 2048 + kh * HD_;
        x0 = bf2f(src[t]);
        x1 = bf2f(src[t + 64]);
        dst = Kc + (((size_t)(b * KV_ + kh)) * S_ + s) * HD_;
    }
    dst[t]      = f2bf(x0 * c - x1 * si);
    dst[t + 64] = f2bf(x1 * c + x0 * si);
}

// fused v-LoRA-B + transpose: bf16 qkv v-part -> Vt [B][KV][128][S] bf16
__global__ __launch_bounds__(256) void vconv_t(const u16* __restrict__ qkvb,
                                               const float* __restrict__ t16v,
                                               const float* __restrict__ lbv,
                                               u16* __restrict__ Vt) {
    __shared__ float tile[32][33];
    __shared__ float ts[32][16];
    int s0 = blockIdx.x * 32, d0 = blockIdx.y * 32;
    int bk = blockIdx.z;
    int b = bk >> 2, kvh = bk & 3;
    int t = threadIdx.x;
    #pragma unroll
    for (int p = 0; p < 2; p++) {
        int idx = p * 256 + t;
        ts[idx >> 4][idx & 15] = t16v[(size_t)(b * S_ + s0 + (idx >> 4)) * R_ + (idx & 15)];
    }
    int r = t >> 3, c4 = (t & 7) * 4;
    ushort4 v4 = *(const ushort4*)(qkvb + (size_t)(b * S_ + s0 + r) * NQKV + 2560 + kvh * HD_ + d0 + c4);
    __syncthreads();
    float vv[4] = {bf2f(v4.x), bf2f(v4.y), bf2f(v4.z), bf2f(v4.w)};
    #pragma unroll
    for (int e = 0; e < 4; e++) {
        int d = kvh * HD_ + d0 + c4 + e;
        const float4* lr = (const float4*)(lbv + (size_t)d * R_);
        float l = 0.f;
        #pragma unroll
        for (int r4 = 0; r4 < 4; r4++) {
            float4 w = lr[r4];
            l += w.x*ts[r][r4*4] + w.y*ts[r][r4*4+1] + w.z*ts[r][r4*4+2] + w.w*ts[r][r4*4+3];
        }
        vv[e] += 2.0f * l;
    }
    tile[r][c4] = vv[0]; tile[r][c4+1] = vv[1]; tile[r][c4+2] = vv[2]; tile[r][c4+3] = vv[3];
    __syncthreads();
    int dr = t >> 3, s4 = (t & 7) * 4;
    ushort4 o;
    o.x = f2bf(tile[s4][dr]);   o.y = f2bf(tile[s4+1][dr]);
    o.z = f2bf(tile[s4+2][dr]); o.w = f2bf(tile[s4+3][dr]);
    *(ushort4*)(Vt + (((size_t)(b * KV_ + kvh)) * HD_ + d0 + dr) * S_ + s0 + s4) = o;
}

// ------------------------------------------------------------------
// grid-union kernel: blocks [0,512) = flash attention (LPT);
// blocks [512,4608) = wg+wu transpose-convert into W' (independent work).
__global__ __launch_bounds__(512) void flash_conv(const u16* __restrict__ Qc,
                                                  const u16* __restrict__ Kc,
                                                  const u16* __restrict__ Vt,
                                                  const int* __restrict__ am,
                                                  u16* __restrict__ o,
                                                  const float* __restrict__ G,
                                                  const float* __restrict__ U,
                                                  u16* __restrict__ Wp) {
    __shared__ __align__(16) char smem[51456];
    int bid = blockIdx.x;
    int tid = threadIdx.x;

    if (bid >= 512) {
        // ---------------- convert branch: 64x64 tile, 512 threads ----------------
        int cid = bid - 512;
        int n0 = (cid & 127) * 64;       // F/64 = 128
        int k0 = (cid >> 7) * 64;        // D/64 = 32
        float (*tile)[65] = (float (*)[65])smem;
        int r = tid >> 4, c4 = (tid & 15) * 4;   // r in 0..31
        #pragma unroll
        for (int slot = 0; slot < 2; slot++) {
            const float* in = slot ? U : G;
            if (slot) __syncthreads();
            #pragma unroll
            for (int p = 0; p < 2; p++) {
                int row = p * 32 + r;
                float4 v = *(const float4*)(in + (size_t)(k0 + row) * F_ + n0 + c4);
                tile[row][c4]   = v.x; tile[row][c4+1] = v.y;
                tile[row][c4+2] = v.z; tile[row][c4+3] = v.w;
            }
            __syncthreads();
            #pragma unroll
            for (int p = 0; p < 2; p++) {
                int n = p * 32 + r;
                int orow = n0 + n;
                int wrow = ((orow >> 7) << 8) + slot * 128 + (orow & 127);
                ushort4 ov;
                ov.x = f2bf(tile[c4][n]);   ov.y = f2bf(tile[c4+1][n]);
                ov.z = f2bf(tile[c4+2][n]); ov.w = f2bf(tile[c4+3][n]);
                *(ushort4*)(Wp + (size_t)wrow * D_ + k0 + c4) = ov;
            }
        }
        return;
    }

    // ---------------- flash branch ----------------
    u16* Ks = (u16*)smem;                       // 64*128
    u16* Vs = (u16*)(smem + 16384);             // 128*64
    u16* Ps = (u16*)(smem + 32768);             // 8*16*72
    int* am_s = (int*)(smem + 51200);           // 64 ints
    int qt = 31 - (bid & 31);                   // LPT
    int kvh = (bid >> 5) & 3, b = bid >> 7;
    int lane = tid & 63, w = tid >> 6;
    int g = lane >> 4, li = lane & 15;
    int h = kvh * 4 + (w & 3);
    int qrow0 = qt * QT2 + (w >> 2) * 16;

    bf16x8 qf[4];
    const u16* qb = Qc + (((size_t)(b * H_ + h)) * S_ + qrow0 + li) * HD_;
    #pragma unroll
    for (int dd = 0; dd < 4; dd++) qf[dd] = *(const bf16x8*)(qb + dd * 32 + g * 8);

    float m_r[4], l_r[4];
    f32x4 oacc[8];
    #pragma unroll
    for (int r = 0; r < 4; r++) { m_r[r] = -1e30f; l_r[r] = 0.f; }
    #pragma unroll
    for (int d = 0; d < 8; d++) oacc[d] = (f32x4){0.f, 0.f, 0.f, 0.f};

    const u16* Kg = Kc + ((size_t)(b * KV_ + kvh)) * S_ * HD_;
    const u16* Vg = Vt + ((size_t)(b * KV_ + kvh)) * HD_ * S_;
    int qg0 = qrow0 + g * 4;
    int nkv = (qt * QT2 + QT2 - 1) >> 6;

    for (int kvt = 0; kvt <= nkv; kvt++) {
        int kv0 = kvt * KBLK;
        #pragma unroll
        for (int qq = 0; qq < 2; qq++) {
            int u = qq * 512 + tid;
            int krow = u >> 4, p = u & 15;
            gload16(Kg + (size_t)(kv0 + krow) * HD_ + (p ^ (krow & 7)) * 8, (char*)Ks + u * 16);
            int vrow = u >> 3, pv = u & 7;
            gload16(Vg + (size_t)vrow * S_ + kv0 + (pv ^ (vrow & 7)) * 8, (char*)Vs + u * 16);
        }
        if (tid < KBLK) am_s[tid] = am[b * S_ + kv0 + tid];
        __syncthreads();

        if (kv0 <= qrow0 + 15) {
            float ps[4][4];
            #pragma unroll
            for (int kt = 0; kt < 4; kt++) {
                f32x4 sa = (f32x4){0.f, 0.f, 0.f, 0.f};
                int row = kt * 16 + li;
                #pragma unroll
                for (int dd = 0; dd < 4; dd++) {
                    int c = dd * 4 + g;
                    bf16x8 kf = *(const bf16x8*)((const char*)Ks + ((row * 16 + (c ^ (row & 7))) << 4));
                    sa = __builtin_amdgcn_mfma_f32_16x16x32_bf16(qf[dd], kf, sa, 0, 0, 0);
                }
                int kcol = kv0 + kt * 16 + li;
                int amok = am_s[kt * 16 + li];
                #pragma unroll
                for (int r = 0; r < 4; r++) {
                    float s = sa[r] * 0.08838834764831845f;
                    ps[kt][r] = (amok && kcol <= qg0 + r) ? s : -1e9f;
                }
            }

            float rmax[4], rsum[4], scl[4];
            #pragma unroll
            for (int r = 0; r < 4; r++)
                rmax[r] = fmaxf(fmaxf(ps[0][r], ps[1][r]), fmaxf(ps[2][r], ps[3][r]));
            #pragma unroll
            for (int msk = 1; msk < 16; msk <<= 1)
                #pragma unroll
                for (int r = 0; r < 4; r++) rmax[r] = fmaxf(rmax[r], __shfl_xor(rmax[r], msk));
            #pragma unroll
            for (int r = 0; r < 4; r++) {
                float mn = fmaxf(m_r[r], rmax[r]);
                scl[r] = __expf(m_r[r] - mn);
                m_r[r] = mn;
                rsum[r] = 0.f;
            }
            #pragma unroll
            for (int kt = 0; kt < 4; kt++)
                #pragma unroll
                for (int r = 0; r < 4; r++) {
                    float p = __expf(ps[kt][r] - m_r[r]);
                    ps[kt][r] = p;
                    rsum[r] += p;
                }
            #pragma unroll
            for (int msk = 1; msk < 16; msk <<= 1)
                #pragma unroll
                for (int r = 0; r < 4; r++) rsum[r] += __shfl_xor(rsum[r], msk);
            #pragma unroll
            for (int r = 0; r < 4; r++) l_r[r] = l_r[r] * scl[r] + rsum[r];
            #pragma unroll
            for (int d = 0; d < 8; d++)
                #pragma unroll
                for (int r = 0; r < 4; r++) oacc[d][r] *= scl[r];

            #pragma unroll
            for (int kt = 0; kt < 4; kt++)
                #pragma unroll
                for (int r = 0; r < 4; r++)
                    Ps[(size_t)w * 16 * 72 + (g * 4 + r) * 72 + kt * 16 + li] = f2bf(ps[kt][r]);
            bf16x8 pf[2];
            #pragma unroll
            for (int ks = 0; ks < 2; ks++)
                pf[ks] = *(const bf16x8*)&Ps[(size_t)w * 16 * 72 + li * 72 + ks * 32 + g * 8];

            #pragma unroll
            for (int dblk = 0; dblk < 8; dblk++) {
                int row = dblk * 16 + li;
                #pragma unroll
                for (int ks = 0; ks < 2; ks++) {
                    int c = ks * 4 + g;
                    bf16x8 vf = *(const bf16x8*)((const char*)Vs + ((row * 8 + (c ^ (row & 7))) << 4));
                    oacc[dblk] = __builtin_amdgcn_mfma_f32_16x16x32_bf16(pf[ks], vf, oacc[dblk], 0, 0, 0);
                }
            }
        }
        __syncthreads();
    }

    float invl[4];
    #pragma unroll
    for (int r = 0; r < 4; r++) invl[r] = 1.f / l_r[r];
    #pragma unroll
    for (int dblk = 0; dblk < 8; dblk++)
        #pragma unroll
        for (int r = 0; r < 4; r++) {
            int qrow = qg0 + r;
            o[(((size_t)b * S_ + qrow) * H_ + h) * HD_ + dblk * 16 + li] =
                f2bf(oacc[dblk][r] * invl[r]);
        }
}

// ------------------------------------------------------------------
__global__ __launch_bounds__(256) void pool_kernel(const float* __restrict__ h,
                                                   const int* __restrict__ am,
                                                   float* __restrict__ out) {
    int b = blockIdx.y;
    int d = blockIdx.x * 256 + threadIdx.x;
    float acc = 0.f, ms = 0.f;
    for (int s = 0; s < S_; s++) {
        float mm = (float)am[b * S_ + s];
        ms  += mm;
        acc += mm * h[((size_t)b * S_ + s) * D_ + d];
    }
    out[(size_t)b * D_ + d] = acc / fmaxf(ms, 1e-9f);
}

// ------------------------------------------------------------------
extern "C" void kernel_launch(void* const* d_in, const int* in_sizes, int n_in,
                              void* d_out, int out_size, void* d_ws, size_t ws_size,
                              hipStream_t stream) {
    const float* embed = (const float*)d_in[0];
    const float* wq    = (const float*)d_in[1];
    const float* wk    = (const float*)d_in[2];
    const float* wv    = (const float*)d_in[3];
    const float* wo    = (const float*)d_in[4];
    const float* laq   = (const float*)d_in[5];
    const float* lbq   = (const float*)d_in[6];
    const float* lav   = (const float*)d_in[7];
    const float* lbv   = (const float*)d_in[8];
    const float* wg    = (const float*)d_in[9];
    const float* wu    = (const float*)d_in[10];
    const float* wd    = (const float*)d_in[11];
    const float* n1    = (const float*)d_in[12];
    const float* n2    = (const float*)d_in[13];
    const float* nf    = (const float*)d_in[14];
    const int*   ids   = (const int*)d_in[15];
    const int*   am    = (const int*)d_in[16];
    float* out = (float*)d_out;

    char* base = (char*)d_ws;
    float* x     = (float*)base;                          // 33.55 MB f32
    u16*   hbf   = (u16*)(base + 33554432);               // 16.78 MB bf16
    u16*   obf   = (u16*)(base + 50331648);               // 16.78 MB bf16
    char*  Rg    = base + 67108864;                       // 67.11 MB multi-purpose
    u16*   qkvb  = (u16*)Rg;                              // 25.17 MB bf16 [4096][3072]
    u16*   wQKVO = (u16*)(Rg + 27262976);                 // 20.97 MB bf16 [5120][2048]
    float* t16v  = (float*)(base + 117440512);            // 0.26 MB (Rg tail, dead before act)
    u16*   act   = (u16*)Rg;                              // 67.11 MB bf16 (after attn)
    float* hf    = (float*)Rg;                            // final norm f32 (after MLP)
    float* t16q  = (float*)(base + 134217728);            // 0.26 MB
    u16*   wT0   = (u16*)(base + 134479872);              // 64 MB as W' / wd^T
    u16*   Qc    = (u16*)(base + 201588736);              // 16.78 MB bf16
    u16*   Kc    = (u16*)(base + 218365952);              // 4.19 MB bf16
    u16*   Vtb   = (u16*)(base + 222560256);              // 4.19 MB bf16
    // total ~226.8 MB

    embed_kernel<<<BS_, 256, 0, stream>>>(embed, ids, x);

    for (int l = 0; l < NL_; l++) {
        const float* wql = wq + (size_t)l * D_ * D_;
        const float* wkl = wk + (size_t)l * D_ * (KV_*HD_);
        const float* wvl = wv + (size_t)l * D_ * (KV_*HD_);
        const float* wol = wo + (size_t)l * D_ * D_;
        const float* wgl = wg + (size_t)l * D_ * F_;
        const float* wul = wu + (size_t)l * D_ * F_;
        const float* wdl = wd + (size_t)l * F_ * D_;

        rmsnorm_kernel<1><<<BS_, 256, 0, stream>>>(x, n1 + (size_t)l * D_, hbf);

        // q/k/v/o weight convert into wQKVO (scratch inside Rg) + qkv projection
        convt_qkv<<<dim3(32, 32, 4), 256, 0, stream>>>(wql, wkl, wvl, wol, wQKVO);
        gemm_bt_bf16<<<dim3(NQKV/128, BS_/128), 256, 0, stream>>>(hbf, wQKVO, qkvb, NQKV, D_);

        // LoRA-A (q and v fused); LoRA-B fused into rope/vconv
        lora_a2<<<dim3(BS_/16, 2), 256, 0, stream>>>(hbf, laq + (size_t)l * R_ * D_,
                                                     lav + (size_t)l * R_ * D_, t16q, t16v);

        qkconv_rope<<<dim3(BS_, 5), 256, 0, stream>>>(qkvb, t16q,
                                                      lbq + (size_t)l * D_ * R_, Qc, Kc);
        vconv_t<<<dim3(S_/32, HD_/32, B_*KV_), 256, 0, stream>>>(qkvb, t16v,
                                                                 lbv + (size_t)l * (KV_*HD_) * R_, Vtb);

        // flash attention UNION gate/up weight convert (independent work overlapped)
        flash_conv<<<dim3(512 + 4096), 512, 0, stream>>>(Qc, Kc, Vtb, am, obf,
                                                         wgl, wul, wT0);

        // o projection via ring GEMM (reads wQKVO, still intact; act not yet written)
        gemm_down_ring<<<dim3(D_/128, BS_/256), 512, 0, stream>>>(obf, wQKVO + (size_t)3072 * D_, x, D_, D_);

        // MLP
        rmsnorm_kernel<1><<<BS_, 256, 0, stream>>>(x, n2 + (size_t)l * D_, hbf);
        gemm_gateup8<<<dim3((2*F_)/256, BS_/256), 512, 0, stream>>>(hbf, wT0, act, F_, D_);
        convt_kernel<<<dim3(D_/64, F_/64), 256, 0, stream>>>(wdl, wT0, F_, D_);
        gemm_down_ring<<<dim3(D_/128, BS_/256), 512, 0, stream>>>(act, wT0, x, D_, F_);
    }

    rmsnorm_kernel<0><<<BS_, 256, 0, stream>>>(x, nf, hf);
    pool_kernel<<<dim3(D_/256, B_), 256, 0, stream>>>(hf, am, out);
}

// Round 15
// 1828.049 us; speedup vs baseline: 1.0580x; 1.0580x over previous
//
#include <hip/hip_runtime.h>
#include <math.h>

#define B_  4
#define S_  1024
#define D_  2048
#define NL_ 2
#define H_  16
#define KV_ 4
#define F_  8192
#define R_  16
#define HD_ 128
#define BS_ (B_*S_)   // 4096 tokens
#define QT2 32
#define KBLK 64
#define NQKV 3072     // q(2048) + k(512) + v(512)

typedef unsigned short u16;
typedef __attribute__((ext_vector_type(8))) __bf16 bf16x8;
typedef __attribute__((ext_vector_type(4))) float  f32x4;

__device__ __forceinline__ u16 f2bf(float f) {
    unsigned x = __float_as_uint(f);
    unsigned r = (x + 0x7fffu + ((x >> 16) & 1u)) >> 16;   // RNE
    return (u16)r;
}
__device__ __forceinline__ float bf2f(u16 u) {
    return __uint_as_float(((unsigned)u) << 16);
}

// async global->LDS, 16B per lane. LDS dest must be linear (base + lane*16).
__device__ __forceinline__ void gload16(const void* g, void* l) {
    __builtin_amdgcn_global_load_lds((const __attribute__((address_space(1))) void*)g,
                                     (__attribute__((address_space(3))) void*)l, 16, 0, 0);
}

// ------------------------------------------------------------------
__global__ void embed_kernel(const float* __restrict__ embed,
                             const int* __restrict__ ids,
                             float* __restrict__ x) {
    int tok = blockIdx.x;
    int id  = ids[tok];
    const float4* src = (const float4*)(embed + (size_t)id * D_);
    float4*       dst = (float4*)(x + (size_t)tok * D_);
    for (int i = threadIdx.x; i < D_/4; i += blockDim.x) dst[i] = src[i];
}

// ------------------------------------------------------------------
template<int OUTBF>
__global__ __launch_bounds__(256) void rmsnorm_kernel(const float* __restrict__ x,
                                                      const float* __restrict__ w,
                                                      void* __restrict__ out) {
    int row = blockIdx.x;
    const float4* xr = (const float4*)(x + (size_t)row * D_);
    float ss = 0.f;
    for (int i = threadIdx.x; i < D_/4; i += 256) {
        float4 v = xr[i];
        ss += v.x*v.x + v.y*v.y + v.z*v.z + v.w*v.w;
    }
    __shared__ float red[4];
    for (int off = 32; off; off >>= 1) ss += __shfl_down(ss, off);
    if ((threadIdx.x & 63) == 0) red[threadIdx.x >> 6] = ss;
    __syncthreads();
    float tot = red[0] + red[1] + red[2] + red[3];
    float scale = rsqrtf(tot / (float)D_ + 1e-5f);
    const float4* w4 = (const float4*)w;
    for (int i = threadIdx.x; i < D_/4; i += 256) {
        float4 v = xr[i], g = w4[i];
        float a = v.x*scale*g.x, b = v.y*scale*g.y, c = v.z*scale*g.z, d = v.w*scale*g.w;
        if (OUTBF) {
            ushort4 o; o.x = f2bf(a); o.y = f2bf(b); o.z = f2bf(c); o.w = f2bf(d);
            ((ushort4*)((u16*)out + (size_t)row * D_))[i] = o;
        } else {
            float4 o; o.x = a; o.y = b; o.z = c; o.w = d;
            ((float4*)((float*)out + (size_t)row * D_))[i] = o;
        }
    }
}

// ------------------------------------------------------------------
// 64x64 transpose + f32->bf16: in [K][N] f32 -> out [N][K] bf16
__global__ __launch_bounds__(256) void convt_kernel(const float* __restrict__ in,
                                                    u16* __restrict__ outT,
                                                    int K, int N) {
    __shared__ float tile[64][65];
    int k0 = blockIdx.y * 64, n0 = blockIdx.x * 64;
    int t = threadIdx.x, r = t >> 4, c4 = (t & 15) * 4;
    #pragma unroll
    for (int p = 0; p < 4; p++) {
        float4 v = *(const float4*)(in + (size_t)(k0 + p * 16 + r) * N + n0 + c4);
        tile[p*16+r][c4]   = v.x; tile[p*16+r][c4+1] = v.y;
        tile[p*16+r][c4+2] = v.z; tile[p*16+r][c4+3] = v.w;
    }
    __syncthreads();
    #pragma unroll
    for (int p = 0; p < 4; p++) {
        int n = p * 16 + r;
        ushort4 o;
        o.x = f2bf(tile[c4][n]);   o.y = f2bf(tile[c4+1][n]);
        o.z = f2bf(tile[c4+2][n]); o.w = f2bf(tile[c4+3][n]);
        *(ushort4*)(outT + (size_t)(n0 + n) * K + k0 + c4) = o;
    }
}

// fused wq/wk/wv/wo transpose-convert into WqkvoT (o at rows 3072..5120).
__global__ __launch_bounds__(256) void convt_qkv(const float* __restrict__ wq,
                                                 const float* __restrict__ wk,
                                                 const float* __restrict__ wv,
                                                 const float* __restrict__ wo,
                                                 u16* __restrict__ outT) {
    int z = blockIdx.z;
    int N = (z == 0 || z == 3) ? 2048 : 512;
    if (blockIdx.x * 64 >= N) return;
    const float* in = (z == 0) ? wq : (z == 1 ? wk : (z == 2 ? wv : wo));
    size_t roff = (z == 0) ? 0 : (z == 1 ? 2048 : (z == 2 ? 2560 : 3072));
    u16* out = outT + roff * D_;
    __shared__ float tile[64][65];
    int k0 = blockIdx.y * 64, n0 = blockIdx.x * 64;
    int t = threadIdx.x, r = t >> 4, c4 = (t & 15) * 4;
    #pragma unroll
    for (int p = 0; p < 4; p++) {
        float4 v = *(const float4*)(in + (size_t)(k0 + p * 16 + r) * N + n0 + c4);
        tile[p*16+r][c4]   = v.x; tile[p*16+r][c4+1] = v.y;
        tile[p*16+r][c4+2] = v.z; tile[p*16+r][c4+3] = v.w;
    }
    __syncthreads();
    #pragma unroll
    for (int p = 0; p < 4; p++) {
        int n = p * 16 + r;
        ushort4 o;
        o.x = f2bf(tile[c4][n]);   o.y = f2bf(tile[c4+1][n]);
        o.z = f2bf(tile[c4+2][n]); o.w = f2bf(tile[c4+3][n]);
        *(ushort4*)(out + (size_t)(n0 + n) * D_ + k0 + c4) = o;
    }
}

// fused wg+wu transpose-convert with G/U row interleave into W' [16384][2048].
__global__ __launch_bounds__(256) void convt_gu2(const float* __restrict__ G,
                                                 const float* __restrict__ U,
                                                 u16* __restrict__ outT) {
    __shared__ float tile[64][65];
    int k0 = blockIdx.y * 64, n0 = blockIdx.x * 64;
    int t = threadIdx.x, r = t >> 4, c4 = (t & 15) * 4;
    #pragma unroll
    for (int slot = 0; slot < 2; slot++) {
        const float* in = slot ? U : G;
        if (slot) __syncthreads();
        #pragma unroll
        for (int p = 0; p < 4; p++) {
            float4 v = *(const float4*)(in + (size_t)(k0 + p * 16 + r) * F_ + n0 + c4);
            tile[p*16+r][c4]   = v.x; tile[p*16+r][c4+1] = v.y;
            tile[p*16+r][c4+2] = v.z; tile[p*16+r][c4+3] = v.w;
        }
        __syncthreads();
        #pragma unroll
        for (int p = 0; p < 4; p++) {
            int n = p * 16 + r;
            int orow = n0 + n;
            int wrow = ((orow >> 7) << 8) + slot * 128 + (orow & 127);
            ushort4 o;
            o.x = f2bf(tile[c4][n]);   o.y = f2bf(tile[c4+1][n]);
            o.z = f2bf(tile[c4+2][n]); o.w = f2bf(tile[c4+3][n]);
            *(ushort4*)(outT + (size_t)wrow * D_ + k0 + c4) = o;
        }
    }
}

// ------------------------------------------------------------------
// MFMA GEMM, B transposed, bf16 output: C[M,N] = A @ Bt^T (qkv projection)
__global__ __launch_bounds__(256) void gemm_bt_bf16(const u16* __restrict__ A,
                                                    const u16* __restrict__ Bt,
                                                    u16* __restrict__ C,
                                                    int N, int K) {
    __shared__ __align__(16) u16 As[128*64];
    __shared__ __align__(16) u16 Bs[128*64];
    int tid = threadIdx.x, lane = tid & 63;
    int wid = tid >> 6, wm = wid >> 1, wn = wid & 1;
    int m0 = blockIdx.y * 128, n0 = blockIdx.x * 128;
    const u16* Ab = A  + (size_t)m0 * K;
    const u16* Bb = Bt + (size_t)n0 * K;
    f32x4 acc[4][4] = {};
    for (int k0 = 0; k0 < K; k0 += 64) {
        #pragma unroll
        for (int qq = 0; qq < 4; qq++) {
            int u = qq * 256 + tid;
            int row = u >> 3, cu = u & 7, scu = cu ^ (row & 7);
            size_t goff = (size_t)row * K + k0 + scu * 8;
            gload16(Ab + goff, (char*)As + u * 16);
            gload16(Bb + goff, (char*)Bs + u * 16);
        }
        __syncthreads();
        #pragma unroll
        for (int kk = 0; kk < 2; kk++) {
            int cu = kk * 4 + (lane >> 4);
            bf16x8 af[4], bfr[4];
            #pragma unroll
            for (int i = 0; i < 4; i++) {
                int ar = wm * 64 + i * 16 + (lane & 15);
                af[i]  = *(const bf16x8*)((const char*)As + (((ar << 3) | (cu ^ (ar & 7))) << 4));
                int br = wn * 64 + i * 16 + (lane & 15);
                bfr[i] = *(const bf16x8*)((const char*)Bs + (((br << 3) | (cu ^ (br & 7))) << 4));
            }
            #pragma unroll
            for (int i = 0; i < 4; i++)
                #pragma unroll
                for (int j = 0; j < 4; j++)
                    acc[i][j] = __builtin_amdgcn_mfma_f32_16x16x32_bf16(af[i], bfr[j], acc[i][j], 0, 0, 0);
        }
        __syncthreads();
    }
    int r0 = (lane >> 4) * 4, c0 = lane & 15;
    #pragma unroll
    for (int i = 0; i < 4; i++)
        #pragma unroll
        for (int j = 0; j < 4; j++) {
            int row = m0 + wm * 64 + i * 16 + r0;
            int col = n0 + wn * 64 + j * 16 + c0;
            u16* cp = C + (size_t)row * N + col;
            #pragma unroll
            for (int r = 0; r < 4; r++)
                cp[(size_t)r * N] = f2bf(acc[i][j][r]);
        }
}

// ------------------------------------------------------------------
// 256x256 fused gate/up GEMM over W' [16384][2048], 4-phase ring schedule.
__global__ __launch_bounds__(512) void gemm_gateup8(const u16* __restrict__ A,
                                                    const u16* __restrict__ Wt,
                                                    u16* __restrict__ act,
                                                    int Nact, int K) {
    __shared__ __align__(16) u16 ring[2][4][8192];   // [op][slot] 16KB slots = 128 KiB
    int tid = threadIdx.x, lane = tid & 63;
    int w = tid >> 6;
    int wm = w >> 2, wn = w & 3;
    int g = lane >> 4, li = lane & 15;
    int m0 = blockIdx.y * 256, n0 = blockIdx.x * 256;
    const u16* Ab = A  + (size_t)m0 * K;
    const u16* Bb = Wt + (size_t)n0 * K;
    int nt = K >> 6;

    f32x4 acc[8][4] = {};

    #define STG(s, t_, kh, P)                                                        \
        do {                                                                         \
            int u_ = (P) * 512 + tid;                                                \
            int j_ = u_ >> 3, cc_ = u_ & 7;                                          \
            int sc_ = cc_ ^ (j_ & 7);                                                \
            int row_ = 2 * j_ + (sc_ >> 2);                                          \
            int kc_ = (t_) * 64 + (kh) * 32 + (sc_ & 3) * 8;                         \
            gload16(Ab + (size_t)row_ * K + kc_, (char*)&ring[0][s][0] + u_ * 16);   \
            gload16(Bb + (size_t)row_ * K + kc_, (char*)&ring[1][s][0] + u_ * 16);   \
        } while (0)

    #define FRAG(op, s, r) (*(const bf16x8*)((const char*)&ring[op][s][0] +          \
        (((((r) >> 1) << 3) | (((((r) & 1) << 2) | g) ^ (((r) >> 1) & 7))) << 4)))

    STG(0, 0, 0, 0); STG(0, 0, 0, 1);
    STG(1, 0, 1, 0); STG(1, 0, 1, 1);
    STG(2, 1, 0, 0); STG(2, 1, 0, 1);

    for (int t = 0; t < nt; t++) {
        int s0  = (2 * t) & 3;
        int s1  = (2 * t + 1) & 3;
        int sW0 = (2 * t + 3) & 3;
        int sW1 = s0;
        bf16x8 afA[4], afB[4], bfr[4];

        // ---- phase 0 ----
        if (t == nt - 1) asm volatile("s_waitcnt vmcnt(4)" ::: "memory");
        else             asm volatile("s_waitcnt vmcnt(8)" ::: "memory");
        __builtin_amdgcn_s_barrier();
        __builtin_amdgcn_sched_barrier(0);
        #pragma unroll
        for (int j = 0; j < 4; j++) bfr[j] = FRAG(1, s0, wn * 64 + j * 16 + li);
        #pragma unroll
        for (int i = 0; i < 4; i++) afA[i] = FRAG(0, s0, wm * 128 + i * 16 + li);
        if (t + 1 < nt) STG(sW0, t + 1, 1, 0);
        asm volatile("s_waitcnt lgkmcnt(0)" ::: "memory");
        __builtin_amdgcn_sched_barrier(0);
        __builtin_amdgcn_s_setprio(1);
        #pragma unroll
        for (int i = 0; i < 4; i++)
            #pragma unroll
            for (int j = 0; j < 4; j++)
                acc[i][j] = __builtin_amdgcn_mfma_f32_16x16x32_bf16(afA[i], bfr[j], acc[i][j], 0, 0, 0);
        __builtin_amdgcn_s_setprio(0);
        #pragma unroll
        for (int i = 0; i < 4; i++) afB[i] = FRAG(0, s0, wm * 128 + 64 + i * 16 + li);
        __builtin_amdgcn_sched_barrier(0);

        // ---- phase 1 ----
        __builtin_amdgcn_s_barrier();
        __builtin_amdgcn_sched_barrier(0);
        if (t + 1 < nt) STG(sW0, t + 1, 1, 1);
        asm volatile("s_waitcnt lgkmcnt(0)" ::: "memory");
        __builtin_amdgcn_sched_barrier(0);
        __builtin_amdgcn_s_setprio(1);
        #pragma unroll
        for (int i = 0; i < 4; i++)
            #pragma unroll
            for (int j = 0; j < 4; j++)
                acc[4 + i][j] = __builtin_amdgcn_mfma_f32_16x16x32_bf16(afB[i], bfr[j], acc[4 + i][j], 0, 0, 0);
        __builtin_amdgcn_s_setprio(0);

        // ---- phase 2 ----
        if (t == nt - 1) asm volatile("s_waitcnt vmcnt(0)" ::: "memory");
        else             asm volatile("s_waitcnt vmcnt(8)" ::: "memory");
        __builtin_amdgcn_s_barrier();
        __builtin_amdgcn_sched_barrier(0);
        #pragma unroll
        for (int j = 0; j < 4; j++) bfr[j] = FRAG(1, s1, wn * 64 + j * 16 + li);
        #pragma unroll
        for (int i = 0; i < 4; i++) afA[i] = FRAG(0, s1, wm * 128 + i * 16 + li);
        if (t + 2 < nt) STG(sW1, t + 2, 0, 0);
        asm volatile("s_waitcnt lgkmcnt(0)" ::: "memory");
        __builtin_amdgcn_sched_barrier(0);
        __builtin_amdgcn_s_setprio(1);
        #pragma unroll
        for (int i = 0; i < 4; i++)
            #pragma unroll
            for (int j = 0; j < 4; j++)
                acc[i][j] = __builtin_amdgcn_mfma_f32_16x16x32_bf16(afA[i], bfr[j], acc[i][j], 0, 0, 0);
        __builtin_amdgcn_s_setprio(0);
        #pragma unroll
        for (int i = 0; i < 4; i++) afB[i] = FRAG(0, s1, wm * 128 + 64 + i * 16 + li);
        __builtin_amdgcn_sched_barrier(0);

        // ---- phase 3 ----
        __builtin_amdgcn_s_barrier();
        __builtin_amdgcn_sched_barrier(0);
        if (t + 2 < nt) STG(sW1, t + 2, 0, 1);
        asm volatile("s_waitcnt lgkmcnt(0)" ::: "memory");
        __builtin_amdgcn_sched_barrier(0);
        __builtin_amdgcn_s_setprio(1);
        #pragma unroll
        for (int i = 0; i < 4; i++)
            #pragma unroll
            for (int j = 0; j < 4; j++)
                acc[4 + i][j] = __builtin_amdgcn_mfma_f32_16x16x32_bf16(afB[i], bfr[j], acc[4 + i][j], 0, 0, 0);
        __builtin_amdgcn_s_setprio(0);
    }
    #undef STG
    #undef FRAG

    // ---- epilogue: U-waves dump acc to LDS, G-waves fuse silu(g)*u ----
    __syncthreads();
    float* X = (float*)&ring[0][0][0];
    if (wn >= 2) {
        float* Rr = X + (size_t)(wm * 2 + (wn - 2)) * 8192;
        #pragma unroll
        for (int i = 0; i < 8; i++)
            #pragma unroll
            for (int j = 0; j < 4; j++)
                #pragma unroll
                for (int r = 0; r < 4; r++) {
                    int row = i * 16 + g * 4 + r;
                    int col = j * 16 + li;
                    Rr[row * 64 + (col ^ (((row >> 2) & 3) << 4))] = acc[i][j][r];
                }
    }
    __syncthreads();
    if (wn < 2) {
        const float* Rr = X + (size_t)(wm * 2 + wn) * 8192;
        int colbase = (n0 >> 1) + wn * 64;
        #pragma unroll
        for (int i = 0; i < 8; i++)
            #pragma unroll
            for (int j = 0; j < 4; j++)
                #pragma unroll
                for (int r = 0; r < 4; r++) {
                    int row = i * 16 + g * 4 + r;
                    int col = j * 16 + li;
                    float gv = acc[i][j][r];
                    float uv = Rr[row * 64 + (col ^ (((row >> 2) & 3) << 4))];
                    float s = gv / (1.f + __expf(-gv));
                    act[(size_t)(m0 + wm * 128 + row) * Nact + colbase + col] = f2bf(s * uv);
                }
    }
}

// ------------------------------------------------------------------
// ring GEMM (ACC += into f32 C): M256 x N128 tile, 4-slot ring, 2 phases/K-tile,
// counted vmcnt(6). Used for down projection AND o projection.
__global__ __launch_bounds__(512) void gemm_down_ring(const u16* __restrict__ A,
                                                      const u16* __restrict__ Bt,
                                                      float* __restrict__ C,
                                                      int N, int K) {
    __shared__ __align__(16) u16 ringA[4][8192];
    __shared__ __align__(16) u16 ringB[4][4096];
    int tid = threadIdx.x, lane = tid & 63;
    int w = tid >> 6;
    int wm = w >> 1, wn = w & 1;
    int g = lane >> 4, li = lane & 15;
    int m0 = blockIdx.y * 256, n0 = blockIdx.x * 128;
    const u16* Ab = A  + (size_t)m0 * K;
    const u16* Bb = Bt + (size_t)n0 * K;
    int nt = K >> 6;

    f32x4 acc[4][4] = {};

    #define STGA(s, t_, kh, P)                                                       \
        do {                                                                         \
            int u_ = (P) * 512 + tid;                                                \
            int j_ = u_ >> 3, cc_ = u_ & 7;                                          \
            int sc_ = cc_ ^ (j_ & 7);                                                \
            int row_ = 2 * j_ + (sc_ >> 2);                                          \
            int kc_ = (t_) * 64 + (kh) * 32 + (sc_ & 3) * 8;                         \
            gload16(Ab + (size_t)row_ * K + kc_, (char*)&ringA[s][0] + u_ * 16);     \
        } while (0)
    #define STGB(s, t_, kh)                                                          \
        do {                                                                         \
            int u_ = tid;                                                            \
            int j_ = u_ >> 3, cc_ = u_ & 7;                                          \
            int sc_ = cc_ ^ (j_ & 7);                                                \
            int row_ = 2 * j_ + (sc_ >> 2);                                          \
            int kc_ = (t_) * 64 + (kh) * 32 + (sc_ & 3) * 8;                         \
            gload16(Bb + (size_t)row_ * K + kc_, (char*)&ringB[s][0] + u_ * 16);     \
        } while (0)

    #define FRAGA(s, r) (*(const bf16x8*)((const char*)&ringA[s][0] +                \
        (((((r) >> 1) << 3) | (((((r) & 1) << 2) | g) ^ (((r) >> 1) & 7))) << 4)))
    #define FRAGB(s, r) (*(const bf16x8*)((const char*)&ringB[s][0] +                \
        (((((r) >> 1) << 3) | (((((r) & 1) << 2) | g) ^ (((r) >> 1) & 7))) << 4)))

    STGA(0, 0, 0, 0); STGA(0, 0, 0, 1); STGB(0, 0, 0);
    STGA(1, 0, 1, 0); STGA(1, 0, 1, 1); STGB(1, 0, 1);
    STGA(2, 1, 0, 0); STGA(2, 1, 0, 1); STGB(2, 1, 0);

    for (int t = 0; t < nt; t++) {
        int s0  = (2 * t) & 3;
        int s1  = (2 * t + 1) & 3;
        int sW0 = (2 * t + 3) & 3;
        int sW1 = s0;
        bf16x8 af[4], bfr[4];

        // ---- phase 0: kh0 ----
        if (t == nt - 1) asm volatile("s_waitcnt vmcnt(3)" ::: "memory");
        else             asm volatile("s_waitcnt vmcnt(6)" ::: "memory");
        __builtin_amdgcn_s_barrier();
        __builtin_amdgcn_sched_barrier(0);
        #pragma unroll
        for (int j = 0; j < 4; j++) bfr[j] = FRAGB(s0, wn * 64 + j * 16 + li);
        #pragma unroll
        for (int i = 0; i < 4; i++) af[i] = FRAGA(s0, wm * 64 + i * 16 + li);
        if (t + 1 < nt) { STGA(sW0, t + 1, 1, 0); STGA(sW0, t + 1, 1, 1); STGB(sW0, t + 1, 1); }
        asm volatile("s_waitcnt lgkmcnt(0)" ::: "memory");
        __builtin_amdgcn_sched_barrier(0);
        __builtin_amdgcn_s_setprio(1);
        #pragma unroll
        for (int i = 0; i < 4; i++)
            #pragma unroll
            for (int j = 0; j < 4; j++)
                acc[i][j] = __builtin_amdgcn_mfma_f32_16x16x32_bf16(af[i], bfr[j], acc[i][j], 0, 0, 0);
        __builtin_amdgcn_s_setprio(0);

        // ---- phase 1: kh1 ----
        if (t == nt - 1) asm volatile("s_waitcnt vmcnt(0)" ::: "memory");
        else             asm volatile("s_waitcnt vmcnt(6)" ::: "memory");
        __builtin_amdgcn_s_barrier();
        __builtin_amdgcn_sched_barrier(0);
        #pragma unroll
        for (int j = 0; j < 4; j++) bfr[j] = FRAGB(s1, wn * 64 + j * 16 + li);
        #pragma unroll
        for (int i = 0; i < 4; i++) af[i] = FRAGA(s1, wm * 64 + i * 16 + li);
        if (t + 2 < nt) { STGA(sW1, t + 2, 0, 0); STGA(sW1, t + 2, 0, 1); STGB(sW1, t + 2, 0); }
        asm volatile("s_waitcnt lgkmcnt(0)" ::: "memory");
        __builtin_amdgcn_sched_barrier(0);
        __builtin_amdgcn_s_setprio(1);
        #pragma unroll
        for (int i = 0; i < 4; i++)
            #pragma unroll
            for (int j = 0; j < 4; j++)
                acc[i][j] = __builtin_amdgcn_mfma_f32_16x16x32_bf16(af[i], bfr[j], acc[i][j], 0, 0, 0);
        __builtin_amdgcn_s_setprio(0);
    }
    #undef STGA
    #undef STGB
    #undef FRAGA
    #undef FRAGB

    int r0 = g * 4, c0 = li;
    #pragma unroll
    for (int i = 0; i < 4; i++)
        #pragma unroll
        for (int j = 0; j < 4; j++) {
            int row = m0 + wm * 64 + i * 16 + r0;
            int col = n0 + wn * 64 + j * 16 + c0;
            float* cp = C + (size_t)row * N + col;
            #pragma unroll
            for (int r = 0; r < 4; r++)
                cp[(size_t)r * N] += acc[i][j][r];
        }
}

// ------------------------------------------------------------------
// LoRA-A, fused q+v (h is bf16)
__global__ __launch_bounds__(256) void lora_a2(const u16* __restrict__ h,
                                               const float* __restrict__ laq,
                                               const float* __restrict__ lav,
                                               float* __restrict__ t16q,
                                               float* __restrict__ t16v) {
    const float* la = blockIdx.y ? lav : laq;
    float* t16 = blockIdx.y ? t16v : t16q;
    int r = threadIdx.x >> 4;
    int c = threadIdx.x & 15;
    int row = blockIdx.x * 16 + r;
    const ushort4* hr = (const ushort4*)(h + (size_t)row * D_);
    const float4* lr = (const float4*)(la + (size_t)c * D_);
    float acc = 0.f;
    #pragma unroll 4
    for (int i = 0; i < D_/4; i++) {
        ushort4 a = hr[i]; float4 b = lr[i];
        acc += bf2f(a.x)*b.x + bf2f(a.y)*b.y + bf2f(a.z)*b.z + bf2f(a.w)*b.w;
    }
    t16[(size_t)row * R_ + c] = acc;
}

// ------------------------------------------------------------------
// fused q-LoRA-B + RoPE from bf16 qkv buffer. grid (BS, H+KV), 64 thr.
__global__ void qkconv_rope(const u16* __restrict__ qkvb,
                            const float* __restrict__ t16q,
                            const float* __restrict__ lbq,
                            u16* __restrict__ Qc, u16* __restrict__ Kc) {
    int tok = blockIdx.x, hh = blockIdx.y, t = threadIdx.x;   // t: 0..63
    int b = tok >> 10, s = tok & (S_ - 1);
    __shared__ float ts[R_];
    if (t < R_) ts[t] = t16q[(size_t)tok * R_ + t];
    __syncthreads();
    float inv = __expf(-(float)t * (13.122363377404328f / 64.0f));
    float f = (float)s * inv;
    float c = __cosf(f), si = __sinf(f);
    float x0, x1;
    u16* dst;
    if (hh < H_) {
        const u16* src = qkvb + (size_t)tok * NQKV + hh * HD_;
        int d0 = hh * HD_ + t;
        float l0 = 0.f, l1 = 0.f;
        const float4* b0 = (const float4*)(lbq + (size_t)d0 * R_);
        const float4* b1 = (const float4*)(lbq + (size_t)(d0 + 64) * R_);
        #pragma unroll
        for (int r4 = 0; r4 < 4; r4++) {
            float4 v0 = b0[r4], v1 = b1[r4];
            l0 += v0.x*ts[r4*4] + v0.y*ts[r4*4+1] + v0.z*ts[r4*4+2] + v0.w*ts[r4*4+3];
            l1 += v1.x*ts[r4*4] + v1.y*ts[r4*4+1] + v1.z*ts[r4*4+2] + v1.w*ts[r4*4+3];
        }
        x0 = bf2f(src[t]) + 2.0f * l0;
        x1 = bf2f(src[t + 64]) + 2.0f * l1;
        dst = Qc + (((size_t)(b * H_ + hh)) * S_ + s) * HD_;
    } else {
        int kh = hh - H_;
        const u16* src = qkvb + (size_t)tok * NQKV + 2048 + kh * HD_;
        x0 = bf2f(src[t]);
        x1 = bf2f(src[t + 64]);
        dst = Kc + (((size_t)(b * KV_ + kh)) * S_ + s) * HD_;
    }
    dst[t]      = f2bf(x0 * c - x1 * si);
    dst[t + 64] = f2bf(x1 * c + x0 * si);
}

// fused v-LoRA-B + transpose: bf16 qkv v-part -> Vt [B][KV][128][S] bf16
__global__ __launch_bounds__(256) void vconv_t(const u16* __restrict__ qkvb,
                                               const float* __restrict__ t16v,
                                               const float* __restrict__ lbv,
                                               u16* __restrict__ Vt) {
    __shared__ float tile[32][33];
    __shared__ float ts[32][16];
    int s0 = blockIdx.x * 32, d0 = blockIdx.y * 32;
    int bk = blockIdx.z;
    int b = bk >> 2, kvh = bk & 3;
    int t = threadIdx.x;
    #pragma unroll
    for (int p = 0; p < 2; p++) {
        int idx = p * 256 + t;
        ts[idx >> 4][idx & 15] = t16v[(size_t)(b * S_ + s0 + (idx >> 4)) * R_ + (idx & 15)];
    }
    int r = t >> 3, c4 = (t & 7) * 4;
    ushort4 v4 = *(const ushort4*)(qkvb + (size_t)(b * S_ + s0 + r) * NQKV + 2560 + kvh * HD_ + d0 + c4);
    __syncthreads();
    float vv[4] = {bf2f(v4.x), bf2f(v4.y), bf2f(v4.z), bf2f(v4.w)};
    #pragma unroll
    for (int e = 0; e < 4; e++) {
        int d = kvh * HD_ + d0 + c4 + e;
        const float4* lr = (const float4*)(lbv + (size_t)d * R_);
        float l = 0.f;
        #pragma unroll
        for (int r4 = 0; r4 < 4; r4++) {
            float4 w = lr[r4];
            l += w.x*ts[r][r4*4] + w.y*ts[r][r4*4+1] + w.z*ts[r][r4*4+2] + w.w*ts[r][r4*4+3];
        }
        vv[e] += 2.0f * l;
    }
    tile[r][c4] = vv[0]; tile[r][c4+1] = vv[1]; tile[r][c4+2] = vv[2]; tile[r][c4+3] = vv[3];
    __syncthreads();
    int dr = t >> 3, s4 = (t & 7) * 4;
    ushort4 o;
    o.x = f2bf(tile[s4][dr]);   o.y = f2bf(tile[s4+1][dr]);
    o.z = f2bf(tile[s4+2][dr]); o.w = f2bf(tile[s4+3][dr]);
    *(ushort4*)(Vt + (((size_t)(b * KV_ + kvh)) * HD_ + d0 + dr) * S_ + s0 + s4) = o;
}

// ------------------------------------------------------------------
// flash attention v3 + LPT ordering
__global__ __launch_bounds__(512) void flash_attn(const u16* __restrict__ Qc,
                                                  const u16* __restrict__ Kc,
                                                  const u16* __restrict__ Vt,
                                                  const int* __restrict__ am,
                                                  u16* __restrict__ o) {
    __shared__ __align__(16) u16 Ks[64 * 128];
    __shared__ __align__(16) u16 Vs[128 * 64];
    __shared__ __align__(16) u16 Ps[8][16][72];
    __shared__ int am_s[KBLK];
    int qt = gridDim.x - 1 - blockIdx.x;           // LPT: big blocks first
    int kvh = blockIdx.y, b = blockIdx.z;
    int tid = threadIdx.x, lane = tid & 63, w = tid >> 6;
    int g = lane >> 4, li = lane & 15;
    int h = kvh * 4 + (w & 3);
    int qrow0 = qt * QT2 + (w >> 2) * 16;

    bf16x8 qf[4];
    const u16* qb = Qc + (((size_t)(b * H_ + h)) * S_ + qrow0 + li) * HD_;
    #pragma unroll
    for (int dd = 0; dd < 4; dd++) qf[dd] = *(const bf16x8*)(qb + dd * 32 + g * 8);

    float m_r[4], l_r[4];
    f32x4 oacc[8];
    #pragma unroll
    for (int r = 0; r < 4; r++) { m_r[r] = -1e30f; l_r[r] = 0.f; }
    #pragma unroll
    for (int d = 0; d < 8; d++) oacc[d] = (f32x4){0.f, 0.f, 0.f, 0.f};

    const u16* Kg = Kc + ((size_t)(b * KV_ + kvh)) * S_ * HD_;
    const u16* Vg = Vt + ((size_t)(b * KV_ + kvh)) * HD_ * S_;
    int qg0 = qrow0 + g * 4;
    int nkv = (qt * QT2 + QT2 - 1) >> 6;

    for (int kvt = 0; kvt <= nkv; kvt++) {
        int kv0 = kvt * KBLK;
        #pragma unroll
        for (int qq = 0; qq < 2; qq++) {
            int u = qq * 512 + tid;
            int krow = u >> 4, p = u & 15;
            gload16(Kg + (size_t)(kv0 + krow) * HD_ + (p ^ (krow & 7)) * 8, (char*)Ks + u * 16);
            int vrow = u >> 3, pv = u & 7;
            gload16(Vg + (size_t)vrow * S_ + kv0 + (pv ^ (vrow & 7)) * 8, (char*)Vs + u * 16);
        }
        if (tid < KBLK) am_s[tid] = am[b * S_ + kv0 + tid];
        __syncthreads();

        if (kv0 <= qrow0 + 15) {
            float ps[4][4];
            #pragma unroll
            for (int kt = 0; kt < 4; kt++) {
                f32x4 sa = (f32x4){0.f, 0.f, 0.f, 0.f};
                int row = kt * 16 + li;
                #pragma unroll
                for (int dd = 0; dd < 4; dd++) {
                    int c = dd * 4 + g;
                    bf16x8 kf = *(const bf16x8*)((const char*)Ks + ((row * 16 + (c ^ (row & 7))) << 4));
                    sa = __builtin_amdgcn_mfma_f32_16x16x32_bf16(qf[dd], kf, sa, 0, 0, 0);
                }
                int kcol = kv0 + kt * 16 + li;
                int amok = am_s[kt * 16 + li];
                #pragma unroll
                for (int r = 0; r < 4; r++) {
                    float s = sa[r] * 0.08838834764831845f;
                    ps[kt][r] = (amok && kcol <= qg0 + r) ? s : -1e9f;
                }
            }

            float rmax[4], rsum[4], scl[4];
            #pragma unroll
            for (int r = 0; r < 4; r++)
                rmax[r] = fmaxf(fmaxf(ps[0][r], ps[1][r]), fmaxf(ps[2][r], ps[3][r]));
            #pragma unroll
            for (int msk = 1; msk < 16; msk <<= 1)
                #pragma unroll
                for (int r = 0; r < 4; r++) rmax[r] = fmaxf(rmax[r], __shfl_xor(rmax[r], msk));
            #pragma unroll
            for (int r = 0; r < 4; r++) {
                float mn = fmaxf(m_r[r], rmax[r]);
                scl[r] = __expf(m_r[r] - mn);
                m_r[r] = mn;
                rsum[r] = 0.f;
            }
            #pragma unroll
            for (int kt = 0; kt < 4; kt++)
                #pragma unroll
                for (int r = 0; r < 4; r++) {
                    float p = __expf(ps[kt][r] - m_r[r]);
                    ps[kt][r] = p;
                    rsum[r] += p;
                }
            #pragma unroll
            for (int msk = 1; msk < 16; msk <<= 1)
                #pragma unroll
                for (int r = 0; r < 4; r++) rsum[r] += __shfl_xor(rsum[r], msk);
            #pragma unroll
            for (int r = 0; r < 4; r++) l_r[r] = l_r[r] * scl[r] + rsum[r];
            #pragma unroll
            for (int d = 0; d < 8; d++)
                #pragma unroll
                for (int r = 0; r < 4; r++) oacc[d][r] *= scl[r];

            #pragma unroll
            for (int kt = 0; kt < 4; kt++)
                #pragma unroll
                for (int r = 0; r < 4; r++)
                    Ps[w][g * 4 + r][kt * 16 + li] = f2bf(ps[kt][r]);
            bf16x8 pf[2];
            #pragma unroll
            for (int ks = 0; ks < 2; ks++)
                pf[ks] = *(const bf16x8*)&Ps[w][li][ks * 32 + g * 8];

            #pragma unroll
            for (int dblk = 0; dblk < 8; dblk++) {
                int row = dblk * 16 + li;
                #pragma unroll
                for (int ks = 0; ks < 2; ks++) {
                    int c = ks * 4 + g;
                    bf16x8 vf = *(const bf16x8*)((const char*)Vs + ((row * 8 + (c ^ (row & 7))) << 4));
                    oacc[dblk] = __builtin_amdgcn_mfma_f32_16x16x32_bf16(pf[ks], vf, oacc[dblk], 0, 0, 0);
                }
            }
        }
        __syncthreads();
    }

    float invl[4];
    #pragma unroll
    for (int r = 0; r < 4; r++) invl[r] = 1.f / l_r[r];
    #pragma unroll
    for (int dblk = 0; dblk < 8; dblk++)
        #pragma unroll
        for (int r = 0; r < 4; r++) {
            int qrow = qg0 + r;
            o[(((size_t)b * S_ + qrow) * H_ + h) * HD_ + dblk * 16 + li] =
                f2bf(oacc[dblk][r] * invl[r]);
        }
}

// ------------------------------------------------------------------
// two-stage masked mean pool
__global__ __launch_bounds__(256) void pool_partial(const float* __restrict__ h,
                                                    const int* __restrict__ am,
                                                    float* __restrict__ pws,
                                                    float* __restrict__ msws) {
    int b = blockIdx.y, z = blockIdx.z;
    int d = blockIdx.x * 256 + threadIdx.x;
    int sbase = z * 128;
    float acc = 0.f;
    for (int s = 0; s < 128; s++) {
        float mm = (float)am[b * S_ + sbase + s];
        acc += mm * h[((size_t)b * S_ + sbase + s) * D_ + d];
    }
    pws[((size_t)(b * 8 + z)) * D_ + d] = acc;
    if (blockIdx.x == 0 && threadIdx.x == 0) {
        float ms = 0.f;
        for (int s = 0; s < 128; s++) ms += (float)am[b * S_ + sbase + s];
        msws[b * 8 + z] = ms;
    }
}

__global__ __launch_bounds__(256) void pool_final(const float* __restrict__ pws,
                                                  const float* __restrict__ msws,
                                                  float* __restrict__ out) {
    int b = blockIdx.y;
    int d = blockIdx.x * 256 + threadIdx.x;
    float acc = 0.f, ms = 0.f;
    #pragma unroll
    for (int z = 0; z < 8; z++) {
        acc += pws[((size_t)(b * 8 + z)) * D_ + d];
        ms  += msws[b * 8 + z];
    }
    out[(size_t)b * D_ + d] = acc / fmaxf(ms, 1e-9f);
}

// ------------------------------------------------------------------
extern "C" void kernel_launch(void* const* d_in, const int* in_sizes, int n_in,
                              void* d_out, int out_size, void* d_ws, size_t ws_size,
                              hipStream_t stream) {
    const float* embed = (const float*)d_in[0];
    const float* wq    = (const float*)d_in[1];
    const float* wk    = (const float*)d_in[2];
    const float* wv    = (const float*)d_in[3];
    const float* wo    = (const float*)d_in[4];
    const float* laq   = (const float*)d_in[5];
    const float* lbq   = (const float*)d_in[6];
    const float* lav   = (const float*)d_in[7];
    const float* lbv   = (const float*)d_in[8];
    const float* wg    = (const float*)d_in[9];
    const float* wu    = (const float*)d_in[10];
    const float* wd    = (const float*)d_in[11];
    const float* n1    = (const float*)d_in[12];
    const float* n2    = (const float*)d_in[13];
    const float* nf    = (const float*)d_in[14];
    const int*   ids   = (const int*)d_in[15];
    const int*   am    = (const int*)d_in[16];
    float* out = (float*)d_out;

    char* base = (char*)d_ws;
    float* x    = (float*)base;                          // 33.55 MB f32
    u16*   hbf  = (u16*)(base + 33554432);               // 16.78 MB bf16
    u16*   obf  = (u16*)(base + 50331648);               // 16.78 MB bf16
    char*  Rg   = base + 67108864;                       // 67.11 MB multi-purpose
    u16*   qkvb = (u16*)Rg;                              // 25.17 MB bf16 [4096][3072]
    float* t16v = (float*)(base + 117440512);            // 0.26 MB (Rg tail)
    float* pws  = (float*)(base + 117440512);            // reused at final pool
    float* msws = (float*)(base + 117702656);            // 128 B
    u16*   act  = (u16*)Rg;                              // 67.11 MB bf16 (after attn)
    float* hf   = (float*)Rg;                            // final norm f32 (after MLP)
    float* t16q = (float*)(base + 134217728);            // 0.26 MB
    u16*   wT0  = (u16*)(base + 134479872);              // 64 MB as WqkvoT / W' / wd^T
    u16*   Qc   = (u16*)(base + 201588736);              // 16.78 MB bf16
    u16*   Kc   = (u16*)(base + 218365952);              // 4.19 MB bf16
    u16*   Vtb  = (u16*)(base + 222560256);              // 4.19 MB bf16
    // total ~226.8 MB

    embed_kernel<<<BS_, 256, 0, stream>>>(embed, ids, x);

    for (int l = 0; l < NL_; l++) {
        const float* wql = wq + (size_t)l * D_ * D_;
        const float* wkl = wk + (size_t)l * D_ * (KV_*HD_);
        const float* wvl = wv + (size_t)l * D_ * (KV_*HD_);
        const float* wol = wo + (size_t)l * D_ * D_;
        const float* wgl = wg + (size_t)l * D_ * F_;
        const float* wul = wu + (size_t)l * D_ * F_;
        const float* wdl = wd + (size_t)l * F_ * D_;

        rmsnorm_kernel<1><<<BS_, 256, 0, stream>>>(x, n1 + (size_t)l * D_, hbf);

        // merged q/k/v/o weight convert + qkv projection (bf16 output)
        convt_qkv<<<dim3(32, 32, 4), 256, 0, stream>>>(wql, wkl, wvl, wol, wT0);
        gemm_bt_bf16<<<dim3(NQKV/128, BS_/128), 256, 0, stream>>>(hbf, wT0, qkvb, NQKV, D_);

        // LoRA-A (q and v fused); LoRA-B fused into rope/vconv
        lora_a2<<<dim3(BS_/16, 2), 256, 0, stream>>>(hbf, laq + (size_t)l * R_ * D_,
                                                     lav + (size_t)l * R_ * D_, t16q, t16v);

        qkconv_rope<<<dim3(BS_, H_ + KV_), 64, 0, stream>>>(qkvb, t16q,
                                                            lbq + (size_t)l * D_ * R_, Qc, Kc);
        vconv_t<<<dim3(S_/32, HD_/32, B_*KV_), 256, 0, stream>>>(qkvb, t16v,
                                                                 lbv + (size_t)l * (KV_*HD_) * R_, Vtb);

        flash_attn<<<dim3(S_/QT2, KV_, B_), 512, 0, stream>>>(Qc, Kc, Vtb, am, obf);

        // o projection via ring GEMM (weights at rows [3072,5120) of wT0)
        gemm_down_ring<<<dim3(D_/128, BS_/256), 512, 0, stream>>>(obf, wT0 + (size_t)3072 * D_, x, D_, D_);

        // MLP
        rmsnorm_kernel<1><<<BS_, 256, 0, stream>>>(x, n2 + (size_t)l * D_, hbf);
        convt_gu2<<<dim3(F_/64, D_/64), 256, 0, stream>>>(wgl, wul, wT0);
        gemm_gateup8<<<dim3((2*F_)/256, BS_/256), 512, 0, stream>>>(hbf, wT0, act, F_, D_);
        convt_kernel<<<dim3(D_/64, F_/64), 256, 0, stream>>>(wdl, wT0, F_, D_);
        gemm_down_ring<<<dim3(D_/128, BS_/256), 512, 0, stream>>>(act, wT0, x, D_, F_);
    }

    rmsnorm_kernel<0><<<BS_, 256, 0, stream>>>(x, nf, hf);
    pool_partial<<<dim3(D_/256, B_, 8), 256, 0, stream>>>(hf, am, pws, msws);
    pool_final<<<dim3(D_/256, B_), 256, 0, stream>>>(pws, msws, out);
}